// Round 10
// baseline (215.633 us; speedup 1.0000x reference)
//
#include <hip/hip_runtime.h>

#define THREADS 256
#define G1 256          // partition blocks (R9 lesson: write-run length >> occupancy)
#define NBMAX 128       // max coarse buckets (1024-node buckets, n <= 128k)
#define CAP 20480       // slotted bpack capacity per bucket (mean ~16.4k, +32 sigma)

using bf16x8 = __attribute__((ext_vector_type(8))) short;
using f32x4 = __attribute__((ext_vector_type(4))) float;

// bf16 helpers (self-contained, RNE)
static __device__ __forceinline__ unsigned short f2bf(float f) {
  unsigned u = __float_as_uint(f);
  unsigned r = (u + 0x7fff + ((u >> 16) & 1)) >> 16;
  return (unsigned short)r;
}
static __device__ __forceinline__ float bflo(unsigned w) {
  return __uint_as_float(w << 16);
}
static __device__ __forceinline__ float bfhi(unsigned w) {
  return __uint_as_float(w & 0xffff0000u);
}
static __device__ __forceinline__ unsigned pk2(float a, float b) {
  return (unsigned)f2bf(a) | ((unsigned)f2bf(b) << 16);
}

// ======= single-pass slotted partition into 1024-node buckets ======================
// 98 buckets -> per-block runs of ~64 edges (256B) per bucket: line-friendly scatter
// (R9 A/B: 8B runs -> 46MB WRITE; 32B runs -> 25.6MB; 256B should be ~8MB).
// One global atomicAdd per (block,bucket) reserves contiguous slot ranges.
// Also zeroes the h1b/h2b guard rows (block 0).

__launch_bounds__(256)
__global__ void k_partition1(const int* __restrict__ src, const int* __restrict__ dst,
                             int* __restrict__ gcur, int* __restrict__ bpack, int e,
                             int NB, int chunk, unsigned* __restrict__ h1b,
                             unsigned* __restrict__ h2b, int n) {
  __shared__ int hist[NBMAX];
  int blk = blockIdx.x, t = threadIdx.x;
  if (blk == 0) {
    if (t < 32) h1b[(size_t)n * 32 + t] = 0u;
    else if (t < 48) h2b[(size_t)n * 16 + (t - 32)] = 0u;
  }
  if (t < NB) hist[t] = 0;
  __syncthreads();
  int beg = blk * chunk;
  int stop = min(e, beg + chunk);
  for (int j = beg + t; j < stop; j += 256) atomicAdd(&hist[dst[j] >> 10], 1);
  __syncthreads();
  // reserve: hist[i] becomes this block's base offset within bucket i
  if (t < NB) {
    int c = hist[t];
    hist[t] = (c > 0) ? atomicAdd(&gcur[t], c) : 0;
  }
  __syncthreads();
  for (int j = beg + t; j < stop; j += 256) {
    int s = src[j];
    int d = dst[j];
    int b = d >> 10;
    int pos = atomicAdd(&hist[b], 1);
    if (pos < CAP) bpack[(size_t)b * CAP + pos] = (s << 10) | (d & 1023);
  }
}

// ======= bucket CSR: 1024-node buckets built fully in LDS ==========================
// Per block: load bucket edges (<=20480 ints, 80KB LDS), count 1024 in-degrees,
// block-scan, scatter LDS->global coalesced-ish. ~90KB static LDS (gfx950 ok).

__launch_bounds__(256)
__global__ void k_bucket_csr2(const int* __restrict__ bpack,
                              const int* __restrict__ gcur, int* __restrict__ rp,
                              float* __restrict__ dinv, int* __restrict__ csr_src,
                              int n, int e, int NB) {
  __shared__ int cl[1024];
  __shared__ int cur[1024];
  __shared__ int ss[256];
  __shared__ int sb[NBMAX + 1];
  __shared__ int buf[CAP];
  int blk = blockIdx.x, t = threadIdx.x;
  // bucket bases: serial LDS scan of NB (<=128) sizes by t0
  if (t < NB) sb[t + 1] = gcur[t];
  if (t == 0) sb[0] = 0;
  for (int i = t; i < 1024; i += 256) cl[i] = 0;
  __syncthreads();
  if (t == 0)
    for (int i = 1; i <= NB; ++i) sb[i] += sb[i - 1];
  __syncthreads();
  int base = sb[blk];
  int cnt = sb[blk + 1] - base;
  if (cnt > CAP) cnt = CAP;  // overflow guard (never hit at +32 sigma margin)
  const int* bsrc = bpack + (size_t)blk * CAP;
  for (int j = t; j < cnt; j += 256) {
    int p = bsrc[j];
    buf[j] = p;
    atomicAdd(&cl[p & 1023], 1);
  }
  __syncthreads();
  // exclusive scan of 1024 in-degrees, 4/thread contiguous
  int b4 = t * 4;
  int v4[4];
  int sum = 0;
#pragma unroll
  for (int k = 0; k < 4; ++k) {
    v4[k] = cl[b4 + k];
    sum += v4[k];
  }
  ss[t] = sum;
  __syncthreads();
  int mine = sum;
  for (int off = 1; off < 256; off <<= 1) {
    int y = (t >= off) ? ss[t - off] : 0;
    __syncthreads();
    ss[t] += y;
    __syncthreads();
  }
  int run = ss[t] - mine;
#pragma unroll
  for (int k = 0; k < 4; ++k) {
    int own = v4[k];
    int v = (blk << 10) + b4 + k;
    if (v < n) {
      rp[v] = base + run;
      dinv[v] = rsqrtf((float)own + 1.0f);
    }
    cur[b4 + k] = base + run;
    run += own;
  }
  __syncthreads();
  for (int j = t; j < cnt; j += 256) {
    int p = buf[j];
    int pos = atomicAdd(&cur[p & 1023], 1);
    csr_src[pos] = p >> 10;
  }
  if (blk == 0 && t == 0) rp[n] = e;
}

// ======================= GEMM1 (MFMA): h1b[n][64](bf16) = dinv[r]*(x @ W1^T) ======

__launch_bounds__(256)
__global__ void k_gemm1(const float* __restrict__ x, const float* __restrict__ W1,
                        const float* __restrict__ dinv, unsigned short* __restrict__ h1b,
                        int n) {
  __shared__ uint4 sXb[64 * 16];                       // 16 KB
  __shared__ uint4 sWb[64 * 16];                       // 16 KB
  __shared__ __align__(16) unsigned short sOut[64 * 64];  // 8 KB
  int t = threadIdx.x;
  const float4* x4 = (const float4*)x;
  const float4* W14 = (const float4*)W1;
  int rbase = blockIdx.x * 64;
#pragma unroll
  for (int p = 0; p < 4; ++p) {
    int q = t + 256 * p;
    int r = q >> 4, s = q & 15;
    int gr = rbase + r;
    float4 v0 = make_float4(0.f, 0.f, 0.f, 0.f), v1 = v0;
    if (gr < n) {
      v0 = x4[(size_t)gr * 32 + s * 2];
      v1 = x4[(size_t)gr * 32 + s * 2 + 1];
    }
    uint4 pk;
    pk.x = pk2(v0.x, v0.y);
    pk.y = pk2(v0.z, v0.w);
    pk.z = pk2(v1.x, v1.y);
    pk.w = pk2(v1.z, v1.w);
    sXb[r * 16 + (s ^ (r & 15))] = pk;
  }
#pragma unroll
  for (int p = 0; p < 4; ++p) {
    int q = t + 256 * p;
    int c = q >> 4, s = q & 15;
    float4 v0 = W14[c * 32 + s * 2];
    float4 v1 = W14[c * 32 + s * 2 + 1];
    uint4 pk;
    pk.x = pk2(v0.x, v0.y);
    pk.y = pk2(v0.z, v0.w);
    pk.z = pk2(v1.x, v1.y);
    pk.w = pk2(v1.z, v1.w);
    sWb[c * 16 + (s ^ (c & 15))] = pk;
  }
  __syncthreads();
  int lane = t & 63;
  int w = t >> 6;
  int l16 = lane & 15, quad = lane >> 4;
  int arow = w * 16 + l16;
  f32x4 acc0 = {0.f, 0.f, 0.f, 0.f};
  f32x4 acc1 = {0.f, 0.f, 0.f, 0.f};
  f32x4 acc2 = {0.f, 0.f, 0.f, 0.f};
  f32x4 acc3 = {0.f, 0.f, 0.f, 0.f};
#pragma unroll
  for (int kc = 0; kc < 4; ++kc) {
    int slot = kc * 4 + quad;
    uint4 ua = sXb[arow * 16 + (slot ^ (arow & 15))];
    bf16x8 a = *(bf16x8*)&ua;
    uint4 ub0 = sWb[(0 + l16) * 16 + (slot ^ l16)];
    uint4 ub1 = sWb[(16 + l16) * 16 + (slot ^ l16)];
    uint4 ub2 = sWb[(32 + l16) * 16 + (slot ^ l16)];
    uint4 ub3 = sWb[(48 + l16) * 16 + (slot ^ l16)];
    acc0 = __builtin_amdgcn_mfma_f32_16x16x32_bf16(a, *(bf16x8*)&ub0, acc0, 0, 0, 0);
    acc1 = __builtin_amdgcn_mfma_f32_16x16x32_bf16(a, *(bf16x8*)&ub1, acc1, 0, 0, 0);
    acc2 = __builtin_amdgcn_mfma_f32_16x16x32_bf16(a, *(bf16x8*)&ub2, acc2, 0, 0, 0);
    acc3 = __builtin_amdgcn_mfma_f32_16x16x32_bf16(a, *(bf16x8*)&ub3, acc3, 0, 0, 0);
  }
  float dvr[4];
#pragma unroll
  for (int r = 0; r < 4; ++r) {
    int grow = rbase + w * 16 + quad * 4 + r;
    dvr[r] = (grow < n) ? dinv[grow] : 0.f;
  }
#pragma unroll
  for (int r = 0; r < 4; ++r) {
    int rl = w * 16 + quad * 4 + r;
    sOut[rl * 64 + 0 + l16] = f2bf(acc0[r] * dvr[r]);
    sOut[rl * 64 + 16 + l16] = f2bf(acc1[r] * dvr[r]);
    sOut[rl * 64 + 32 + l16] = f2bf(acc2[r] * dvr[r]);
    sOut[rl * 64 + 48 + l16] = f2bf(acc3[r] * dvr[r]);
  }
  __syncthreads();
#pragma unroll
  for (int p = 0; p < 2; ++p) {
    int q = t + 256 * p;
    int r = q >> 3, s = q & 7;
    int gr = rbase + r;
    if (gr < n)
      *(uint4*)&h1b[(size_t)gr * 64 + s * 8] = *(uint4*)&sOut[r * 64 + s * 8];
  }
}

// ===== fused agg1+gemm2, 32-row tiles: uint4 gather (8 lanes/node), unroll 8 ======

__launch_bounds__(256)
__global__ void k_fused(const unsigned* __restrict__ h1p, const float* __restrict__ b1,
                        const float* __restrict__ W2, const float* __restrict__ dinv,
                        const int* __restrict__ rp, const int* __restrict__ csr_src,
                        unsigned short* __restrict__ h2b, int n) {
  __shared__ uint4 sXb2[32 * 8];                        // 4 KB: 32 rows x 64 bf16
  __shared__ uint4 sWb2[32 * 8];                        // 4 KB
  __shared__ __align__(16) unsigned short sOut2[32 * 32];  // 2 KB
  int t = threadIdx.x;
  int rbase = blockIdx.x * 32;
  const uint4* h1q4 = (const uint4*)h1p;  // row = 8 uint4 (64 bf16)
  const float4* W24 = (const float4*)W2;
  const float4* b14 = (const float4*)b1;
  // stage W2 (32 cols x 64 bf16)
  {
    int c = t >> 3, s2 = t & 7;
    float4 v0 = W24[c * 16 + s2 * 2];
    float4 v1 = W24[c * 16 + s2 * 2 + 1];
    uint4 pk;
    pk.x = pk2(v0.x, v0.y);
    pk.y = pk2(v0.z, v0.w);
    pk.z = pk2(v1.x, v1.y);
    pk.w = pk2(v1.z, v1.w);
    sWb2[c * 8 + (s2 ^ (c & 7))] = pk;
  }
  // gather phase: thread = (node r = t>>3, lane = t&7); lane covers feats [8L,8L+8)
  {
    int r = t >> 3;
    int lane = t & 7;
    int v = rbase + r;
    uint4 packed = make_uint4(0u, 0u, 0u, 0u);
    if (v < n) {
      int beg = rp[v], end = rp[v + 1];
      float a0[2][8];
#pragma unroll
      for (int b = 0; b < 2; ++b)
#pragma unroll
        for (int i = 0; i < 8; ++i) a0[b][i] = 0.f;
      {
        uint4 w0 = h1q4[(size_t)v * 8 + lane];  // self (pre-scaled by dinv[v])
        a0[0][0] = bflo(w0.x);
        a0[0][1] = bfhi(w0.x);
        a0[0][2] = bflo(w0.y);
        a0[0][3] = bfhi(w0.y);
        a0[0][4] = bflo(w0.z);
        a0[0][5] = bfhi(w0.z);
        a0[0][6] = bflo(w0.w);
        a0[0][7] = bfhi(w0.w);
      }
      for (int j = beg; j < end; j += 8) {
        int s8[8];
#pragma unroll
        for (int k = 0; k < 8; ++k) s8[k] = csr_src[j + k];
#pragma unroll
        for (int k = 1; k < 8; ++k) s8[k] = (j + k < end) ? s8[k] : n;
        uint4 g[8];
#pragma unroll
        for (int k = 0; k < 8; ++k) g[k] = h1q4[(size_t)s8[k] * 8 + lane];
#pragma unroll
        for (int k = 0; k < 8; ++k) {
          a0[k & 1][0] += bflo(g[k].x);
          a0[k & 1][1] += bfhi(g[k].x);
          a0[k & 1][2] += bflo(g[k].y);
          a0[k & 1][3] += bfhi(g[k].y);
          a0[k & 1][4] += bflo(g[k].z);
          a0[k & 1][5] += bfhi(g[k].z);
          a0[k & 1][6] += bflo(g[k].w);
          a0[k & 1][7] += bfhi(g[k].w);
        }
      }
      float dv = dinv[v];
      float4 bb0 = b14[lane * 2];
      float4 bb1 = b14[lane * 2 + 1];
      float f0 = fmaxf(fmaf(dv, a0[0][0] + a0[1][0], bb0.x), 0.f);
      float f1 = fmaxf(fmaf(dv, a0[0][1] + a0[1][1], bb0.y), 0.f);
      float f2 = fmaxf(fmaf(dv, a0[0][2] + a0[1][2], bb0.z), 0.f);
      float f3 = fmaxf(fmaf(dv, a0[0][3] + a0[1][3], bb0.w), 0.f);
      float f4 = fmaxf(fmaf(dv, a0[0][4] + a0[1][4], bb1.x), 0.f);
      float f5 = fmaxf(fmaf(dv, a0[0][5] + a0[1][5], bb1.y), 0.f);
      float f6 = fmaxf(fmaf(dv, a0[0][6] + a0[1][6], bb1.z), 0.f);
      float f7 = fmaxf(fmaf(dv, a0[0][7] + a0[1][7], bb1.w), 0.f);
      packed.x = pk2(f0, f1);
      packed.y = pk2(f2, f3);
      packed.z = pk2(f4, f5);
      packed.w = pk2(f6, f7);
    }
    sXb2[r * 8 + (lane ^ (r & 7))] = packed;
  }
  __syncthreads();
  // MFMA: 4 warps, 2x2 grid of 16x16 tiles over 32x32 output, K=64
  int lane64 = t & 63;
  int w = t >> 6;
  int wr = w & 1, wc = w >> 1;
  int l16 = lane64 & 15, quad = lane64 >> 4;
  int arow = wr * 16 + l16;
  int bcol = wc * 16 + l16;
  f32x4 acc = {0.f, 0.f, 0.f, 0.f};
#pragma unroll
  for (int kc = 0; kc < 2; ++kc) {
    int slot = kc * 4 + quad;
    uint4 ua = sXb2[arow * 8 + (slot ^ (arow & 7))];
    uint4 ub = sWb2[bcol * 8 + (slot ^ (bcol & 7))];
    acc = __builtin_amdgcn_mfma_f32_16x16x32_bf16(*(bf16x8*)&ua, *(bf16x8*)&ub, acc,
                                                  0, 0, 0);
  }
  float dvr[4];
#pragma unroll
  for (int r = 0; r < 4; ++r) {
    int grow = rbase + wr * 16 + quad * 4 + r;
    dvr[r] = (grow < n) ? dinv[grow] : 0.f;
  }
#pragma unroll
  for (int r = 0; r < 4; ++r) {
    int rl = wr * 16 + quad * 4 + r;
    sOut2[rl * 32 + wc * 16 + l16] = f2bf(acc[r] * dvr[r]);
  }
  __syncthreads();
  if (t < 128) {
    int r = t >> 2, s2 = t & 3;
    int gr = rbase + r;
    if (gr < n)
      *(uint4*)&h2b[(size_t)gr * 32 + s2 * 8] = *(uint4*)&sOut2[r * 32 + s2 * 8];
  }
}

// ======== agg2: bf16 gather, 8 lanes/node x uint2 (4 feats), unroll 8, fused out ====

__launch_bounds__(256)
__global__ void k_agg2(const unsigned* __restrict__ h2p, const float* __restrict__ dinv,
                       const int* __restrict__ rp, const int* __restrict__ csr_src,
                       const float* __restrict__ b2, float* __restrict__ out, int n) {
  int gid = blockIdx.x * 256 + threadIdx.x;
  int v = gid >> 3, f4 = gid & 7;  // uint2 index within row (4 feats)
  if (v >= n) return;
  const uint2* h2q = (const uint2*)h2p;
  int beg = rp[v], end = rp[v + 1];
  uint2 w0 = h2q[(size_t)v * 8 + f4];  // self
  float acc[4][4];
#pragma unroll
  for (int k = 0; k < 4; ++k)
#pragma unroll
    for (int c = 0; c < 4; ++c) acc[k][c] = 0.f;
  acc[0][0] = bflo(w0.x);
  acc[0][1] = bfhi(w0.x);
  acc[0][2] = bflo(w0.y);
  acc[0][3] = bfhi(w0.y);
  for (int j = beg; j < end; j += 8) {
    int s[8];
#pragma unroll
    for (int k = 0; k < 8; ++k) s[k] = csr_src[j + k];
#pragma unroll
    for (int k = 1; k < 8; ++k) s[k] = (j + k < end) ? s[k] : n;
    uint2 g[8];
#pragma unroll
    for (int k = 0; k < 8; ++k) g[k] = h2q[(size_t)s[k] * 8 + f4];
#pragma unroll
    for (int k = 0; k < 8; ++k) {
      acc[k & 3][0] += bflo(g[k].x);
      acc[k & 3][1] += bfhi(g[k].x);
      acc[k & 3][2] += bflo(g[k].y);
      acc[k & 3][3] += bfhi(g[k].y);
    }
  }
  float s0 = (acc[0][0] + acc[1][0]) + (acc[2][0] + acc[3][0]);
  float s1 = (acc[0][1] + acc[1][1]) + (acc[2][1] + acc[3][1]);
  float s2 = (acc[0][2] + acc[1][2]) + (acc[2][2] + acc[3][2]);
  float s3 = (acc[0][3] + acc[1][3]) + (acc[2][3] + acc[3][3]);
  float dv = dinv[v];
  float4 bv = ((const float4*)b2)[f4];
  float4 o;
  o.x = fmaf(dv, s0, bv.x);
  o.y = fmaf(dv, s1, bv.y);
  o.z = fmaf(dv, s2, bv.z);
  o.w = fmaf(dv, s3, bv.w);
  ((float4*)out)[(size_t)v * 8 + f4] = o;
}

// ======================= launcher =======================

extern "C" void kernel_launch(void* const* d_in, const int* in_sizes, int n_in,
                              void* d_out, int out_size, void* d_ws, size_t ws_size,
                              hipStream_t stream) {
  const float* x = (const float*)d_in[0];
  const int* ei = (const int*)d_in[1];
  const float* W1 = (const float*)d_in[2];
  const float* b1 = (const float*)d_in[3];
  const float* W2 = (const float*)d_in[4];
  const float* b2 = (const float*)d_in[5];
  float* out = (float*)d_out;

  const int n = in_sizes[0] / 128;  // 100000
  const int e = in_sizes[1] / 2;    // 1600000
  const int* src = ei;
  const int* dst = ei + e;

  const int NB = (n + 1023) >> 10;        // 1024-node buckets (98)
  const int chunk = (e + G1 - 1) / G1;    // edges per partition block

  char* base = (char*)d_ws;
  size_t off = 0;
  auto alloc = [&](size_t bytes) {
    char* p = base + off;
    off = (off + bytes + 255) & ~(size_t)255;
    return p;
  };
  int* gcur = (int*)alloc(NBMAX * 4);                        // bucket size counters
  int* bpack = (int*)alloc((size_t)NB * CAP * 4);            // slotted buckets (8MB)
  int* rp = (int*)alloc((size_t)(n + 1) * 4);
  int* csr_src = (int*)alloc((size_t)(e + 8) * 4);           // +8 pad for unroll
  float* dinv = (float*)alloc((size_t)n * 4);
  unsigned short* h1b = (unsigned short*)alloc((size_t)(n + 1) * 64 * 2);  // bf16
  unsigned short* h2b = (unsigned short*)alloc((size_t)(n + 1) * 32 * 2);  // bf16

  // CSR build: line-friendly slotted partition + in-LDS bucket CSR
  hipMemsetAsync(gcur, 0, NBMAX * 4, stream);
  k_partition1<<<G1, 256, 0, stream>>>(src, dst, gcur, bpack, e, NB, chunk,
                                       (unsigned*)h1b, (unsigned*)h2b, n);
  k_bucket_csr2<<<NB, 256, 0, stream>>>(bpack, gcur, rp, dinv, csr_src, n, e, NB);

  // layer 1 dense transform
  k_gemm1<<<(n + 63) / 64, 256, 0, stream>>>(x, W1, dinv, h1b, n);
  // fused: agg1 + relu(+b1) + gemm2 -> h2b (32-row tiles, uint4 gather, unroll 8)
  k_fused<<<(n + 31) / 32, 256, 0, stream>>>((const unsigned*)h1b, b1, W2, dinv, rp,
                                             csr_src, h2b, n);
  // layer 2 aggregate + b2 -> out
  {
    long long total = (long long)n * 8;
    k_agg2<<<(int)((total + 255) / 256), 256, 0, stream>>>((const unsigned*)h2b, dinv,
                                                           rp, csr_src, b2, out, n);
  }
}

// Round 11
// 201.133 us; speedup vs baseline: 1.0721x; 1.0721x over previous
//
#include <hip/hip_runtime.h>

#define THREADS 256
#define G1 256          // partition blocks (R9: fewer blocks -> longer write runs)
#define NBMAX 1024      // max coarse buckets (256-node buckets, n <= 256k)
#define CAP 5120        // slotted bpack capacity per bucket (mean ~4092, +16 sigma)

using bf16x8 = __attribute__((ext_vector_type(8))) short;
using f32x4 = __attribute__((ext_vector_type(4))) float;

// bf16 helpers (self-contained, RNE)
static __device__ __forceinline__ unsigned short f2bf(float f) {
  unsigned u = __float_as_uint(f);
  unsigned r = (u + 0x7fff + ((u >> 16) & 1)) >> 16;
  return (unsigned short)r;
}
static __device__ __forceinline__ float bflo(unsigned w) {
  return __uint_as_float(w << 16);
}
static __device__ __forceinline__ float bfhi(unsigned w) {
  return __uint_as_float(w & 0xffff0000u);
}
static __device__ __forceinline__ unsigned pk2(float a, float b) {
  return (unsigned)f2bf(a) | ((unsigned)f2bf(b) << 16);
}

// ======= single-pass slotted partition into 256-node buckets =======================
// R8 (128-node/782 buckets): 32B runs, WRITE 25.6MB, 45us. R10 (1024-node/98):
// 256B runs but CSR starved (98 blocks). Midpoint: 256-node/391 buckets ->
// 64B runs (one line per block-bucket visit) AND 391-block CSR parallelism.
// One global atomicAdd per (block,bucket) reserves contiguous slot ranges.
// Also zeroes the h1b/h2b guard rows (block 0).

__launch_bounds__(256)
__global__ void k_partition1(const int* __restrict__ src, const int* __restrict__ dst,
                             int* __restrict__ gcur, int* __restrict__ bpack, int e,
                             int NB, int chunk, unsigned* __restrict__ h1b,
                             unsigned* __restrict__ h2b, int n) {
  __shared__ int hist[NBMAX];
  int blk = blockIdx.x, t = threadIdx.x;
  if (blk == 0) {
    if (t < 32) h1b[(size_t)n * 32 + t] = 0u;
    else if (t < 48) h2b[(size_t)n * 16 + (t - 32)] = 0u;
  }
  for (int i = t; i < NB; i += 256) hist[i] = 0;
  __syncthreads();
  int beg = blk * chunk;
  int stop = min(e, beg + chunk);
  for (int j = beg + t; j < stop; j += 256) atomicAdd(&hist[dst[j] >> 8], 1);
  __syncthreads();
  // reserve: hist[i] becomes this block's base offset within bucket i
  for (int i = t; i < NB; i += 256) {
    int c = hist[i];
    hist[i] = (c > 0) ? atomicAdd(&gcur[i], c) : 0;
  }
  __syncthreads();
  for (int j = beg + t; j < stop; j += 256) {
    int s = src[j];
    int d = dst[j];
    int b = d >> 8;
    int pos = atomicAdd(&hist[b], 1);
    if (pos < CAP) bpack[(size_t)b * CAP + pos] = (s << 8) | (d & 255);
  }
}

// ======= bucket CSR: 256-node buckets, fully in LDS (391 blocks, ~28KB LDS) ========

__launch_bounds__(256)
__global__ void k_bucket_csr2(const int* __restrict__ bpack,
                              const int* __restrict__ gcur, int* __restrict__ rp,
                              float* __restrict__ dinv, int* __restrict__ csr_src,
                              int n, int e, int NB) {
  __shared__ int cl[256];
  __shared__ int cur[256];
  __shared__ int buf[CAP];
  __shared__ int sb[1025];
  __shared__ int ss[256];
  int blk = blockIdx.x, t = threadIdx.x;
  // exclusive scan of bucket sizes (NB <= 1024), 4/thread
  {
    int b4 = t * 4;
    int v4[4];
    int sum = 0;
#pragma unroll
    for (int k = 0; k < 4; ++k) {
      int i = b4 + k;
      v4[k] = (i < NB) ? gcur[i] : 0;
      sum += v4[k];
    }
    ss[t] = sum;
    __syncthreads();
    int mine = sum;
    for (int off = 1; off < 256; off <<= 1) {
      int y = (t >= off) ? ss[t - off] : 0;
      __syncthreads();
      ss[t] += y;
      __syncthreads();
    }
    int run = ss[t] - mine;
#pragma unroll
    for (int k = 0; k < 4; ++k) {
      sb[b4 + k] = run;
      run += v4[k];
    }
    if (t == 255) sb[1024] = run;
  }
  cl[t] = 0;
  __syncthreads();
  int base = sb[blk];
  int cnt = sb[blk + 1] - base;
  if (cnt > CAP) cnt = CAP;  // overflow guard (never hit at +16 sigma margin)
  const int* bsrc = bpack + (size_t)blk * CAP;
  for (int j = t; j < cnt; j += 256) {
    int p = bsrc[j];
    buf[j] = p;
    atomicAdd(&cl[p & 255], 1);
  }
  __syncthreads();
  // exclusive scan of 256 in-degrees (one per thread)
  int own = cl[t];
  for (int off = 1; off < 256; off <<= 1) {
    int y = (t >= off) ? cl[t - off] : 0;
    __syncthreads();
    cl[t] += y;
    __syncthreads();
  }
  {
    int excl = cl[t] - own;
    int v = (blk << 8) + t;
    if (v < n) {
      rp[v] = base + excl;
      dinv[v] = rsqrtf((float)own + 1.0f);
    }
    cur[t] = base + excl;
  }
  __syncthreads();
  for (int j = t; j < cnt; j += 256) {
    int p = buf[j];
    int pos = atomicAdd(&cur[p & 255], 1);
    csr_src[pos] = p >> 8;
  }
  if (blk == 0 && t == 0) rp[n] = e;
}

// ======================= GEMM1 (MFMA): h1b[n][64](bf16) = dinv[r]*(x @ W1^T) ======

__launch_bounds__(256)
__global__ void k_gemm1(const float* __restrict__ x, const float* __restrict__ W1,
                        const float* __restrict__ dinv, unsigned short* __restrict__ h1b,
                        int n) {
  __shared__ uint4 sXb[64 * 16];                       // 16 KB
  __shared__ uint4 sWb[64 * 16];                       // 16 KB
  __shared__ __align__(16) unsigned short sOut[64 * 64];  // 8 KB
  int t = threadIdx.x;
  const float4* x4 = (const float4*)x;
  const float4* W14 = (const float4*)W1;
  int rbase = blockIdx.x * 64;
#pragma unroll
  for (int p = 0; p < 4; ++p) {
    int q = t + 256 * p;
    int r = q >> 4, s = q & 15;
    int gr = rbase + r;
    float4 v0 = make_float4(0.f, 0.f, 0.f, 0.f), v1 = v0;
    if (gr < n) {
      v0 = x4[(size_t)gr * 32 + s * 2];
      v1 = x4[(size_t)gr * 32 + s * 2 + 1];
    }
    uint4 pk;
    pk.x = pk2(v0.x, v0.y);
    pk.y = pk2(v0.z, v0.w);
    pk.z = pk2(v1.x, v1.y);
    pk.w = pk2(v1.z, v1.w);
    sXb[r * 16 + (s ^ (r & 15))] = pk;
  }
#pragma unroll
  for (int p = 0; p < 4; ++p) {
    int q = t + 256 * p;
    int c = q >> 4, s = q & 15;
    float4 v0 = W14[c * 32 + s * 2];
    float4 v1 = W14[c * 32 + s * 2 + 1];
    uint4 pk;
    pk.x = pk2(v0.x, v0.y);
    pk.y = pk2(v0.z, v0.w);
    pk.z = pk2(v1.x, v1.y);
    pk.w = pk2(v1.z, v1.w);
    sWb[c * 16 + (s ^ (c & 15))] = pk;
  }
  __syncthreads();
  int lane = t & 63;
  int w = t >> 6;
  int l16 = lane & 15, quad = lane >> 4;
  int arow = w * 16 + l16;
  f32x4 acc0 = {0.f, 0.f, 0.f, 0.f};
  f32x4 acc1 = {0.f, 0.f, 0.f, 0.f};
  f32x4 acc2 = {0.f, 0.f, 0.f, 0.f};
  f32x4 acc3 = {0.f, 0.f, 0.f, 0.f};
#pragma unroll
  for (int kc = 0; kc < 4; ++kc) {
    int slot = kc * 4 + quad;
    uint4 ua = sXb[arow * 16 + (slot ^ (arow & 15))];
    bf16x8 a = *(bf16x8*)&ua;
    uint4 ub0 = sWb[(0 + l16) * 16 + (slot ^ l16)];
    uint4 ub1 = sWb[(16 + l16) * 16 + (slot ^ l16)];
    uint4 ub2 = sWb[(32 + l16) * 16 + (slot ^ l16)];
    uint4 ub3 = sWb[(48 + l16) * 16 + (slot ^ l16)];
    acc0 = __builtin_amdgcn_mfma_f32_16x16x32_bf16(a, *(bf16x8*)&ub0, acc0, 0, 0, 0);
    acc1 = __builtin_amdgcn_mfma_f32_16x16x32_bf16(a, *(bf16x8*)&ub1, acc1, 0, 0, 0);
    acc2 = __builtin_amdgcn_mfma_f32_16x16x32_bf16(a, *(bf16x8*)&ub2, acc2, 0, 0, 0);
    acc3 = __builtin_amdgcn_mfma_f32_16x16x32_bf16(a, *(bf16x8*)&ub3, acc3, 0, 0, 0);
  }
  float dvr[4];
#pragma unroll
  for (int r = 0; r < 4; ++r) {
    int grow = rbase + w * 16 + quad * 4 + r;
    dvr[r] = (grow < n) ? dinv[grow] : 0.f;
  }
#pragma unroll
  for (int r = 0; r < 4; ++r) {
    int rl = w * 16 + quad * 4 + r;
    sOut[rl * 64 + 0 + l16] = f2bf(acc0[r] * dvr[r]);
    sOut[rl * 64 + 16 + l16] = f2bf(acc1[r] * dvr[r]);
    sOut[rl * 64 + 32 + l16] = f2bf(acc2[r] * dvr[r]);
    sOut[rl * 64 + 48 + l16] = f2bf(acc3[r] * dvr[r]);
  }
  __syncthreads();
#pragma unroll
  for (int p = 0; p < 2; ++p) {
    int q = t + 256 * p;
    int r = q >> 3, s = q & 7;
    int gr = rbase + r;
    if (gr < n)
      *(uint4*)&h1b[(size_t)gr * 64 + s * 8] = *(uint4*)&sOut[r * 64 + s * 8];
  }
}

// ===== fused agg1+gemm2, 32-row tiles: uint4 gather (8 lanes/node), unroll 8 ======

__launch_bounds__(256)
__global__ void k_fused(const unsigned* __restrict__ h1p, const float* __restrict__ b1,
                        const float* __restrict__ W2, const float* __restrict__ dinv,
                        const int* __restrict__ rp, const int* __restrict__ csr_src,
                        unsigned short* __restrict__ h2b, int n) {
  __shared__ uint4 sXb2[32 * 8];                        // 4 KB: 32 rows x 64 bf16
  __shared__ uint4 sWb2[32 * 8];                        // 4 KB
  __shared__ __align__(16) unsigned short sOut2[32 * 32];  // 2 KB
  int t = threadIdx.x;
  int rbase = blockIdx.x * 32;
  const uint4* h1q4 = (const uint4*)h1p;  // row = 8 uint4 (64 bf16)
  const float4* W24 = (const float4*)W2;
  const float4* b14 = (const float4*)b1;
  // stage W2 (32 cols x 64 bf16)
  {
    int c = t >> 3, s2 = t & 7;
    float4 v0 = W24[c * 16 + s2 * 2];
    float4 v1 = W24[c * 16 + s2 * 2 + 1];
    uint4 pk;
    pk.x = pk2(v0.x, v0.y);
    pk.y = pk2(v0.z, v0.w);
    pk.z = pk2(v1.x, v1.y);
    pk.w = pk2(v1.z, v1.w);
    sWb2[c * 8 + (s2 ^ (c & 7))] = pk;
  }
  // gather phase: thread = (node r = t>>3, lane = t&7); lane covers feats [8L,8L+8)
  {
    int r = t >> 3;
    int lane = t & 7;
    int v = rbase + r;
    uint4 packed = make_uint4(0u, 0u, 0u, 0u);
    if (v < n) {
      int beg = rp[v], end = rp[v + 1];
      float a0[2][8];
#pragma unroll
      for (int b = 0; b < 2; ++b)
#pragma unroll
        for (int i = 0; i < 8; ++i) a0[b][i] = 0.f;
      {
        uint4 w0 = h1q4[(size_t)v * 8 + lane];  // self (pre-scaled by dinv[v])
        a0[0][0] = bflo(w0.x);
        a0[0][1] = bfhi(w0.x);
        a0[0][2] = bflo(w0.y);
        a0[0][3] = bfhi(w0.y);
        a0[0][4] = bflo(w0.z);
        a0[0][5] = bfhi(w0.z);
        a0[0][6] = bflo(w0.w);
        a0[0][7] = bfhi(w0.w);
      }
      for (int j = beg; j < end; j += 8) {
        int s8[8];
#pragma unroll
        for (int k = 0; k < 8; ++k) s8[k] = csr_src[j + k];
#pragma unroll
        for (int k = 1; k < 8; ++k) s8[k] = (j + k < end) ? s8[k] : n;
        uint4 g[8];
#pragma unroll
        for (int k = 0; k < 8; ++k) g[k] = h1q4[(size_t)s8[k] * 8 + lane];
#pragma unroll
        for (int k = 0; k < 8; ++k) {
          a0[k & 1][0] += bflo(g[k].x);
          a0[k & 1][1] += bfhi(g[k].x);
          a0[k & 1][2] += bflo(g[k].y);
          a0[k & 1][3] += bfhi(g[k].y);
          a0[k & 1][4] += bflo(g[k].z);
          a0[k & 1][5] += bfhi(g[k].z);
          a0[k & 1][6] += bflo(g[k].w);
          a0[k & 1][7] += bfhi(g[k].w);
        }
      }
      float dv = dinv[v];
      float4 bb0 = b14[lane * 2];
      float4 bb1 = b14[lane * 2 + 1];
      float f0 = fmaxf(fmaf(dv, a0[0][0] + a0[1][0], bb0.x), 0.f);
      float f1 = fmaxf(fmaf(dv, a0[0][1] + a0[1][1], bb0.y), 0.f);
      float f2 = fmaxf(fmaf(dv, a0[0][2] + a0[1][2], bb0.z), 0.f);
      float f3 = fmaxf(fmaf(dv, a0[0][3] + a0[1][3], bb0.w), 0.f);
      float f4 = fmaxf(fmaf(dv, a0[0][4] + a0[1][4], bb1.x), 0.f);
      float f5 = fmaxf(fmaf(dv, a0[0][5] + a0[1][5], bb1.y), 0.f);
      float f6 = fmaxf(fmaf(dv, a0[0][6] + a0[1][6], bb1.z), 0.f);
      float f7 = fmaxf(fmaf(dv, a0[0][7] + a0[1][7], bb1.w), 0.f);
      packed.x = pk2(f0, f1);
      packed.y = pk2(f2, f3);
      packed.z = pk2(f4, f5);
      packed.w = pk2(f6, f7);
    }
    sXb2[r * 8 + (lane ^ (r & 7))] = packed;
  }
  __syncthreads();
  // MFMA: 4 warps, 2x2 grid of 16x16 tiles over 32x32 output, K=64
  int lane64 = t & 63;
  int w = t >> 6;
  int wr = w & 1, wc = w >> 1;
  int l16 = lane64 & 15, quad = lane64 >> 4;
  int arow = wr * 16 + l16;
  int bcol = wc * 16 + l16;
  f32x4 acc = {0.f, 0.f, 0.f, 0.f};
#pragma unroll
  for (int kc = 0; kc < 2; ++kc) {
    int slot = kc * 4 + quad;
    uint4 ua = sXb2[arow * 8 + (slot ^ (arow & 7))];
    uint4 ub = sWb2[bcol * 8 + (slot ^ (bcol & 7))];
    acc = __builtin_amdgcn_mfma_f32_16x16x32_bf16(*(bf16x8*)&ua, *(bf16x8*)&ub, acc,
                                                  0, 0, 0);
  }
  float dvr[4];
#pragma unroll
  for (int r = 0; r < 4; ++r) {
    int grow = rbase + wr * 16 + quad * 4 + r;
    dvr[r] = (grow < n) ? dinv[grow] : 0.f;
  }
#pragma unroll
  for (int r = 0; r < 4; ++r) {
    int rl = wr * 16 + quad * 4 + r;
    sOut2[rl * 32 + wc * 16 + l16] = f2bf(acc[r] * dvr[r]);
  }
  __syncthreads();
  if (t < 128) {
    int r = t >> 2, s2 = t & 3;
    int gr = rbase + r;
    if (gr < n)
      *(uint4*)&h2b[(size_t)gr * 32 + s2 * 8] = *(uint4*)&sOut2[r * 32 + s2 * 8];
  }
}

// ======== agg2: bf16 gather, 8 lanes/node x uint2 (4 feats), unroll 8, fused out ====

__launch_bounds__(256)
__global__ void k_agg2(const unsigned* __restrict__ h2p, const float* __restrict__ dinv,
                       const int* __restrict__ rp, const int* __restrict__ csr_src,
                       const float* __restrict__ b2, float* __restrict__ out, int n) {
  int gid = blockIdx.x * 256 + threadIdx.x;
  int v = gid >> 3, f4 = gid & 7;  // uint2 index within row (4 feats)
  if (v >= n) return;
  const uint2* h2q = (const uint2*)h2p;
  int beg = rp[v], end = rp[v + 1];
  uint2 w0 = h2q[(size_t)v * 8 + f4];  // self
  float acc[4][4];
#pragma unroll
  for (int k = 0; k < 4; ++k)
#pragma unroll
    for (int c = 0; c < 4; ++c) acc[k][c] = 0.f;
  acc[0][0] = bflo(w0.x);
  acc[0][1] = bfhi(w0.x);
  acc[0][2] = bflo(w0.y);
  acc[0][3] = bfhi(w0.y);
  for (int j = beg; j < end; j += 8) {
    int s[8];
#pragma unroll
    for (int k = 0; k < 8; ++k) s[k] = csr_src[j + k];
#pragma unroll
    for (int k = 1; k < 8; ++k) s[k] = (j + k < end) ? s[k] : n;
    uint2 g[8];
#pragma unroll
    for (int k = 0; k < 8; ++k) g[k] = h2q[(size_t)s[k] * 8 + f4];
#pragma unroll
    for (int k = 0; k < 8; ++k) {
      acc[k & 3][0] += bflo(g[k].x);
      acc[k & 3][1] += bfhi(g[k].x);
      acc[k & 3][2] += bflo(g[k].y);
      acc[k & 3][3] += bfhi(g[k].y);
    }
  }
  float s0 = (acc[0][0] + acc[1][0]) + (acc[2][0] + acc[3][0]);
  float s1 = (acc[0][1] + acc[1][1]) + (acc[2][1] + acc[3][1]);
  float s2 = (acc[0][2] + acc[1][2]) + (acc[2][2] + acc[3][2]);
  float s3 = (acc[0][3] + acc[1][3]) + (acc[2][3] + acc[3][3]);
  float dv = dinv[v];
  float4 bv = ((const float4*)b2)[f4];
  float4 o;
  o.x = fmaf(dv, s0, bv.x);
  o.y = fmaf(dv, s1, bv.y);
  o.z = fmaf(dv, s2, bv.z);
  o.w = fmaf(dv, s3, bv.w);
  ((float4*)out)[(size_t)v * 8 + f4] = o;
}

// ======================= launcher =======================

extern "C" void kernel_launch(void* const* d_in, const int* in_sizes, int n_in,
                              void* d_out, int out_size, void* d_ws, size_t ws_size,
                              hipStream_t stream) {
  const float* x = (const float*)d_in[0];
  const int* ei = (const int*)d_in[1];
  const float* W1 = (const float*)d_in[2];
  const float* b1 = (const float*)d_in[3];
  const float* W2 = (const float*)d_in[4];
  const float* b2 = (const float*)d_in[5];
  float* out = (float*)d_out;

  const int n = in_sizes[0] / 128;  // 100000
  const int e = in_sizes[1] / 2;    // 1600000
  const int* src = ei;
  const int* dst = ei + e;

  const int NB = (n + 255) >> 8;          // 256-node buckets (391)
  const int chunk = (e + G1 - 1) / G1;    // edges per partition block

  char* base = (char*)d_ws;
  size_t off = 0;
  auto alloc = [&](size_t bytes) {
    char* p = base + off;
    off = (off + bytes + 255) & ~(size_t)255;
    return p;
  };
  int* gcur = (int*)alloc(NBMAX * 4);                        // bucket size counters
  int* bpack = (int*)alloc((size_t)NB * CAP * 4);            // slotted buckets (8MB)
  int* rp = (int*)alloc((size_t)(n + 1) * 4);
  int* csr_src = (int*)alloc((size_t)(e + 8) * 4);           // +8 pad for unroll
  float* dinv = (float*)alloc((size_t)n * 4);
  unsigned short* h1b = (unsigned short*)alloc((size_t)(n + 1) * 64 * 2);  // bf16
  unsigned short* h2b = (unsigned short*)alloc((size_t)(n + 1) * 32 * 2);  // bf16

  // CSR build: line-friendly slotted partition + in-LDS bucket CSR
  hipMemsetAsync(gcur, 0, NBMAX * 4, stream);
  k_partition1<<<G1, 256, 0, stream>>>(src, dst, gcur, bpack, e, NB, chunk,
                                       (unsigned*)h1b, (unsigned*)h2b, n);
  k_bucket_csr2<<<NB, 256, 0, stream>>>(bpack, gcur, rp, dinv, csr_src, n, e, NB);

  // layer 1 dense transform
  k_gemm1<<<(n + 63) / 64, 256, 0, stream>>>(x, W1, dinv, h1b, n);
  // fused: agg1 + relu(+b1) + gemm2 -> h2b (32-row tiles, uint4 gather, unroll 8)
  k_fused<<<(n + 31) / 32, 256, 0, stream>>>((const unsigned*)h1b, b1, W2, dinv, rp,
                                             csr_src, h2b, n);
  // layer 2 aggregate + b2 -> out
  {
    long long total = (long long)n * 8;
    k_agg2<<<(int)((total + 255) / 256), 256, 0, stream>>>((const unsigned*)h2b, dinv,
                                                           rp, csr_src, b2, out, n);
  }
}